// Round 8
// baseline (333.600 us; speedup 1.0000x reference)
//
#include <hip/hip_runtime.h>
#include <hip/hip_bf16.h>

typedef __attribute__((ext_vector_type(8))) short short8;
typedef __attribute__((ext_vector_type(4))) float f32x4;

#define B_   16
#define O_   512
#define C_   512
#define T_   4096
#define TP   (T_ + 32)     // padded t extent: 16 zero rows each side
#define KT   5
#define BM   128
#define BN   512
#define BK   32
#define NCHUNK (C_/BK)
#define BGRP 33            // real B row-groups: 33 x 16 rows x 64B (+1 pad group)

__device__ __forceinline__ void gload_lds16(const void* g, void* l) {
    __builtin_amdgcn_global_load_lds(
        (const __attribute__((address_space(1))) unsigned int*)g,
        (__attribute__((address_space(3))) unsigned int*)l, 16, 0, 0);
}

// ---------------- fused prep: wrepack (blocks 0..5119) + padzero (5120..6143) ----
__global__ void prep_kernel(const float* __restrict__ w,
                            unsigned short* __restrict__ wb,
                            unsigned short* __restrict__ xt) {
    int bid = blockIdx.x;
    if (bid < 5120) {
        int e   = bid * 256 + threadIdx.x;
        int n   = e / (O_ * C_);
        int rem = e % (O_ * C_);
        int o   = rem / C_;
        int c   = rem % C_;
        float v = w[((size_t)o * C_ + c) * KT + n];
        __hip_bfloat16 h = __float2bfloat16(v);
        wb[e] = *reinterpret_cast<unsigned short*>(&h);
    } else {
        int i = (bid - 5120) * 256 + threadIdx.x;
        int b = i / (32 * C_);
        int r = (i / C_) % 32;
        int c = i % C_;
        int tp = (r < 16) ? r : (T_ + r);
        xt[((size_t)b * TP + tp) * C_ + c] = 0;
    }
}

// ---------------- x transpose: x[b][c][t] f32 -> xT[b][16+t][c] bf16 ----------------
__global__ void xtrans_kernel(const float* __restrict__ x, unsigned short* __restrict__ xt) {
    __shared__ float tile[64][65];
    int b  = blockIdx.z;
    int c0 = blockIdx.y * 64;
    int t0 = blockIdx.x * 64;
    const float* xb = x + ((size_t)b * C_ + c0) * T_ + t0;
#pragma unroll
    for (int p = 0; p < 4; ++p) {
        int idx = p * 256 + threadIdx.x;
        int cl = idx >> 4;
        int tj = (idx & 15) << 2;
        float4 v = *reinterpret_cast<const float4*>(xb + (size_t)cl * T_ + tj);
        tile[cl][tj + 0] = v.x;
        tile[cl][tj + 1] = v.y;
        tile[cl][tj + 2] = v.z;
        tile[cl][tj + 3] = v.w;
    }
    __syncthreads();
    unsigned short* xtb = xt + ((size_t)b * TP + 16 + t0) * C_ + c0;
#pragma unroll
    for (int p = 0; p < 2; ++p) {
        int g  = p * 256 + threadIdx.x;
        int tl = g >> 3;
        int cj = (g & 7) << 3;
        unsigned short tmp[8];
#pragma unroll
        for (int i = 0; i < 8; ++i) {
            __hip_bfloat16 h = __float2bfloat16(tile[cj + i][tl]);
            tmp[i] = *reinterpret_cast<unsigned short*>(&h);
        }
        *reinterpret_cast<short8*>(xtb + (size_t)tl * C_ + cj) =
            *reinterpret_cast<const short8*>(tmp);
    }
}

// ---------------- conv-as-GEMM: A direct from L2 to registers, B via LDS ----------
// Block tile 128(o) x 512(t), BK=32, 8 waves (2M x 4N), wave tile 64x128.
// A (weights, 2.6 MB L2-resident): global->VGPR per-lane dwordx4, 1-tap-ahead
// register prefetch (compiler-counted vmcnt spans the phase barrier).
// B: row-major [528+16][32] LDS, slot swizzle lg ^ ((row>>1)&3) (0-conflict),
// staged via gload_lds at phase 4, drained by one vmcnt(0) per chunk.
#define CHUNK_BODY(CHUNK, PAR)                                                      \
    {                                                                               \
        const int chunk_ = (CHUNK);                                                 \
        const int c0v = chunk_ * BK;                                                \
        const int c1v = (chunk_ + 1 < NCHUNK) ? (chunk_ + 1) * BK : 0;              \
        const unsigned short* bl = b_lds[PAR];                                      \
        _Pragma("unroll")                                                           \
        for (int n = 0; n < KT; ++n) {                                              \
            short8 bf[8];                                                           \
            _Pragma("unroll")                                                       \
            for (int ni = 0; ni < 8; ++ni) {                                        \
                int row = rowb[ni] - n;                                             \
                int off = row * 32 + ((lg ^ ((row >> 1) & 3)) << 3);                \
                bf[ni] = *reinterpret_cast<const short8*>(&bl[off]);                \
            }                                                                       \
            const int nn = (n + 1 == KT) ? 0 : (n + 1);                             \
            const int cc = (n + 1 == KT) ? c1v : c0v;                               \
            _Pragma("unroll")                                                       \
            for (int mi = 0; mi < 4; ++mi)                                          \
                afr[((PAR) + n + 1) & 1][mi] = *reinterpret_cast<const short8*>(    \
                    ag + (size_t)(nn * O_ + mi * 16) * C_ + cc);                    \
            if (n + 1 == KT) {                                                      \
                _Pragma("unroll")                                                   \
                for (int k = 0; k < 5; ++k) {                                       \
                    int j  = wid + 8 * k;                                           \
                    int jj = (j < BGRP) ? j : 0;                                    \
                    int lj = (j < BGRP) ? j : BGRP;                                 \
                    gload_lds16(bg + (size_t)(jj * 16) * C_ + c1v,                  \
                                &b_lds[(PAR) ^ 1][lj * 512]);                       \
                }                                                                   \
            }                                                                       \
            __builtin_amdgcn_s_barrier();                                           \
            __builtin_amdgcn_sched_barrier(0);                                      \
            __builtin_amdgcn_s_setprio(1);                                          \
            _Pragma("unroll")                                                       \
            for (int mi = 0; mi < 4; ++mi)                                          \
                _Pragma("unroll")                                                   \
                for (int ni = 0; ni < 8; ++ni)                                      \
                    acc[mi][ni] = __builtin_amdgcn_mfma_f32_16x16x32_bf16(          \
                        afr[((PAR) + n) & 1][mi], bf[ni], acc[mi][ni], 0, 0, 0);    \
            __builtin_amdgcn_s_setprio(0);                                          \
        }                                                                           \
        asm volatile("s_waitcnt vmcnt(0)" ::: "memory");                            \
        __builtin_amdgcn_s_barrier();                                               \
    }

__global__ __launch_bounds__(512, 2) void conv_gemm_kernel(
        const unsigned short* __restrict__ wb,
        const unsigned short* __restrict__ xt,
        const float* __restrict__ bias,
        float* __restrict__ out) {
    __shared__ unsigned short b_lds[2][(BGRP + 1) * 512];   // 2 x 34816 B

    // XCD-aware bijective swizzle (512 blocks): o-tile innermost so the 4
    // o-tiles sharing a B-panel are consecutive on one XCD.
    int bid  = blockIdx.x;
    int swz  = (bid & 7) * 64 + (bid >> 3);
    int o0   = (swz & 3) * BM;
    int t0   = ((swz >> 2) & 7) * BN;
    int b    = swz >> 5;

    int tid  = threadIdx.x;
    int lane = tid & 63;
    int wid  = tid >> 6;       // 0..7
    int wm   = wid >> 2;       // 0..1  (m-position)
    int wn   = wid & 3;        // 0..3  (n-position)
    int lr   = lane & 15;
    int lg   = lane >> 4;

    // B row bases (tap 0), per ni
    int rowb[8];
#pragma unroll
    for (int ni = 0; ni < 8; ++ni)
        rowb[ni] = wn * 128 + ni * 16 + lr + 4;

    f32x4 acc[4][8];
#pragma unroll
    for (int mi = 0; mi < 4; ++mi)
#pragma unroll
        for (int ni = 0; ni < 8; ++ni)
            acc[mi][ni] = (f32x4)0.0f;

    // A: per-lane global fragment base (L2-resident weights)
    const unsigned short* ag = wb + (size_t)(o0 + wm * 64 + lr) * C_ + lg * 8;
    // B: per-lane staging base (pre-swizzled source)
    int c8 = (lane & 3) ^ ((lane >> 3) & 3);
    const unsigned short* bg = xt + ((size_t)b * TP + (t0 + 14 + (lane >> 2))) * C_ + c8 * 8;

    short8 afr[2][4];

    // ---- prologue: stage B chunk 0; load A tap 0 into afr[0]
#pragma unroll
    for (int k = 0; k < 5; ++k) {
        int j  = wid + 8 * k;
        int jj = (j < BGRP) ? j : 0;
        int lj = (j < BGRP) ? j : BGRP;
        gload_lds16(bg + (size_t)(jj * 16) * C_, &b_lds[0][lj * 512]);
    }
#pragma unroll
    for (int mi = 0; mi < 4; ++mi)
        afr[0][mi] = *reinterpret_cast<const short8*>(ag + (size_t)(mi * 16) * C_);
    asm volatile("s_waitcnt vmcnt(0)" ::: "memory");
    __builtin_amdgcn_s_barrier();

    for (int c2 = 0; c2 < NCHUNK; c2 += 2) {
        CHUNK_BODY(c2, 0);
        CHUNK_BODY(c2 + 1, 1);
    }

    // ---- epilogue: C/D layout col=lane&15, row=(lane>>4)*4+reg
#pragma unroll
    for (int mi = 0; mi < 4; ++mi) {
#pragma unroll
        for (int ni = 0; ni < 8; ++ni) {
            int orow = o0 + wm * 64 + mi * 16 + lg * 4;
            int tcol = t0 + wn * 128 + ni * 16 + lr;
#pragma unroll
            for (int r = 0; r < 4; ++r) {
                out[((size_t)b * O_ + orow + r) * T_ + tcol] =
                    acc[mi][ni][r] + bias[orow + r];
            }
        }
    }
}

extern "C" void kernel_launch(void* const* d_in, const int* in_sizes, int n_in,
                              void* d_out, int out_size, void* d_ws, size_t ws_size,
                              hipStream_t stream) {
    const float* x    = (const float*)d_in[0];
    const float* w    = (const float*)d_in[1];
    const float* bias = (const float*)d_in[2];
    float* out        = (float*)d_out;

    unsigned short* wb  = (unsigned short*)d_ws;            // 2.62 MB
    unsigned short* xtp = wb + (size_t)KT * O_ * C_;        // 16*4128*512 bf16 = 67.7 MB

    prep_kernel<<<6144, 256, 0, stream>>>(w, wb, xtp);
    xtrans_kernel<<<dim3(T_ / 64, C_ / 64, B_), 256, 0, stream>>>(x, xtp);
    conv_gemm_kernel<<<512, 512, 0, stream>>>(wb, xtp, bias, out);
}

// Round 9
// 189.018 us; speedup vs baseline: 1.7649x; 1.7649x over previous
//
#include <hip/hip_runtime.h>
#include <hip/hip_bf16.h>

typedef __attribute__((ext_vector_type(8))) short short8;
typedef __attribute__((ext_vector_type(4))) float f32x4;

#define B_   16
#define O_   512
#define C_   512
#define T_   4096
#define TP   (T_ + 32)     // padded t extent: 16 zero rows each side
#define KT   5
#define BM   128
#define BN   512
#define BK   32
#define NCHUNK (C_/BK)
#define AFR  40            // A fragments: 5 taps x 8 rowblocks, 1024B each
#define BGR  33            // B row-groups: 33 x 16 rows x 64B

__device__ __forceinline__ void gload_lds16(const void* g, void* l) {
    __builtin_amdgcn_global_load_lds(
        (const __attribute__((address_space(1))) unsigned int*)g,
        (__attribute__((address_space(3))) unsigned int*)l, 16, 0, 0);
}

// ---------------- fused prep: wrepack (blocks 0..5119) + padzero (5120..6143) ----
__global__ void prep_kernel(const float* __restrict__ w,
                            unsigned short* __restrict__ wb,
                            unsigned short* __restrict__ xt) {
    int bid = blockIdx.x;
    if (bid < 5120) {
        int e   = bid * 256 + threadIdx.x;
        int n   = e / (O_ * C_);
        int rem = e % (O_ * C_);
        int o   = rem / C_;
        int c   = rem % C_;
        float v = w[((size_t)o * C_ + c) * KT + n];
        __hip_bfloat16 h = __float2bfloat16(v);
        wb[e] = *reinterpret_cast<unsigned short*>(&h);
    } else {
        int i = (bid - 5120) * 256 + threadIdx.x;
        int b = i / (32 * C_);
        int r = (i / C_) % 32;
        int c = i % C_;
        int tp = (r < 16) ? r : (T_ + r);
        xt[((size_t)b * TP + tp) * C_ + c] = 0;
    }
}

// ---------------- x transpose: x[b][c][t] f32 -> xT[b][16+t][c] bf16 ----------------
__global__ void xtrans_kernel(const float* __restrict__ x, unsigned short* __restrict__ xt) {
    __shared__ float tile[64][65];
    int b  = blockIdx.z;
    int c0 = blockIdx.y * 64;
    int t0 = blockIdx.x * 64;
    const float* xb = x + ((size_t)b * C_ + c0) * T_ + t0;
#pragma unroll
    for (int p = 0; p < 4; ++p) {
        int idx = p * 256 + threadIdx.x;
        int cl = idx >> 4;
        int tj = (idx & 15) << 2;
        float4 v = *reinterpret_cast<const float4*>(xb + (size_t)cl * T_ + tj);
        tile[cl][tj + 0] = v.x;
        tile[cl][tj + 1] = v.y;
        tile[cl][tj + 2] = v.z;
        tile[cl][tj + 3] = v.w;
    }
    __syncthreads();
    unsigned short* xtb = xt + ((size_t)b * TP + 16 + t0) * C_ + c0;
#pragma unroll
    for (int p = 0; p < 2; ++p) {
        int g  = p * 256 + threadIdx.x;
        int tl = g >> 3;
        int cj = (g & 7) << 3;
        unsigned short tmp[8];
#pragma unroll
        for (int i = 0; i < 8; ++i) {
            __hip_bfloat16 h = __float2bfloat16(tile[cj + i][tl]);
            tmp[i] = *reinterpret_cast<unsigned short*>(&h);
        }
        *reinterpret_cast<short8*>(xtb + (size_t)tl * C_ + cj) =
            *reinterpret_cast<const short8*>(tmp);
    }
}

// ---------------- conv-as-GEMM, phased (T3) pipeline, compiler-scheduled waits ----
// Block tile 128(o) x 512(t), BK=32, 8 waves, wave tile 128x64 (1M x 8N).
// A: fragment-major LDS (zero-conflict). B: row-major [528][32], XOR slot swizzle.
// Per chunk: 5 phases {12 ds_read; 1-2 gload_lds prefetch; barrier; 32 MFMA}.
// NO explicit lgkmcnt(0)/sched_barrier: compiler emits counted lgkm waits and
// interleaves MFMAs with the LDS read tail (m97-asm-verified behavior).
// vmcnt(0) drained once per chunk.
__global__ __launch_bounds__(512, 2) void conv_gemm_kernel(
        const unsigned short* __restrict__ wb,
        const unsigned short* __restrict__ xt,
        const float* __restrict__ bias,
        float* __restrict__ out) {
    __shared__ unsigned short a_lds[2][AFR * 512];   // 2 x 40960 B
    __shared__ unsigned short b_lds[2][BGR * 512];   // 2 x 33792 B

    // XCD-aware bijective swizzle (512 blocks): o-tile innermost.
    int bid = blockIdx.x;
    int swz = (bid & 7) * 64 + (bid >> 3);
    int o0  = (swz & 3) * BM;
    int t0  = ((swz >> 2) & 7) * BN;
    int b   = swz >> 5;

    int tid  = threadIdx.x;
    int lane = tid & 63;
    int wid  = tid >> 6;       // 0..7 = wave n-position
    int lr   = lane & 15;
    int lg   = lane >> 4;

    // chunk-invariant B read offsets (ushort units)
    int bo[KT][4];
#pragma unroll
    for (int n = 0; n < KT; ++n)
#pragma unroll
        for (int ni = 0; ni < 4; ++ni) {
            int row = wid * 64 + ni * 16 + lr + 4 - n;
            bo[n][ni] = row * 32 + ((lg ^ ((row >> 1) & 3)) << 3);
        }

    f32x4 acc[8][4];
#pragma unroll
    for (int mi = 0; mi < 8; ++mi)
#pragma unroll
        for (int ni = 0; ni < 4; ++ni)
            acc[mi][ni] = (f32x4)0.0f;

    // per-lane global staging bases
    const unsigned short* ag = wb + (size_t)(o0 + lr) * C_ + lg * 8;
    int c8 = (lane & 3) ^ ((lane >> 3) & 3);
    const unsigned short* bg = xt + ((size_t)b * TP + (t0 + 14 + (lane >> 2))) * C_ + c8 * 8;

    // ---- prologue: stage chunk 0 into buffer 0
#pragma unroll
    for (int f = wid; f < AFR; f += 8)
        gload_lds16(ag + (size_t)((f >> 3) * O_ + (f & 7) * 16) * C_, &a_lds[0][f * 512]);
#pragma unroll
    for (int j = wid; j < BGR; j += 8)
        gload_lds16(bg + (size_t)(j * 16) * C_, &b_lds[0][j * 512]);
    asm volatile("s_waitcnt vmcnt(0)" ::: "memory");
    __builtin_amdgcn_s_barrier();

    for (int chunk = 0; chunk < NCHUNK; ++chunk) {
        int cur = chunk & 1;
        int c1  = (chunk + 1) * BK;
        bool pf = (chunk + 1 < NCHUNK);

#pragma unroll
        for (int n = 0; n < KT; ++n) {
            // ---- phase n: read tap n's fragments
            short8 af[8], bf[4];
#pragma unroll
            for (int mi = 0; mi < 8; ++mi)
                af[mi] = *reinterpret_cast<const short8*>(
                    &a_lds[cur][(n * 8 + mi) * 512 + lane * 8]);
#pragma unroll
            for (int ni = 0; ni < 4; ++ni)
                bf[ni] = *reinterpret_cast<const short8*>(&b_lds[cur][bo[n][ni]]);

            // ---- prefetch slice for chunk+1 (1 A group + <=1 B group per wave)
            if (pf) {
                int f = n * 8 + wid;
                gload_lds16(ag + (size_t)((f >> 3) * O_ + (f & 7) * 16) * C_ + c1,
                            &a_lds[cur ^ 1][f * 512]);
                int j = n * 8 + wid;
                if (j < BGR)
                    gload_lds16(bg + (size_t)(j * 16) * C_ + c1, &b_lds[cur ^ 1][j * 512]);
            }

            __builtin_amdgcn_s_barrier();
            // no lgkmcnt(0), no sched_barrier: compiler interleaves counted
            // lgkm waits so MFMAs start as soon as their fragments land.

            __builtin_amdgcn_s_setprio(1);
#pragma unroll
            for (int mi = 0; mi < 8; ++mi)
#pragma unroll
                for (int ni = 0; ni < 4; ++ni)
                    acc[mi][ni] = __builtin_amdgcn_mfma_f32_16x16x32_bf16(
                        af[mi], bf[ni], acc[mi][ni], 0, 0, 0);
            __builtin_amdgcn_s_setprio(0);
        }

        // ---- chunk boundary: ensure next buffer fully staged on all waves
        asm volatile("s_waitcnt vmcnt(0)" ::: "memory");
        __builtin_amdgcn_s_barrier();
    }

    // ---- epilogue: C/D layout col=lane&15, row=(lane>>4)*4+reg
#pragma unroll
    for (int mi = 0; mi < 8; ++mi) {
#pragma unroll
        for (int ni = 0; ni < 4; ++ni) {
            int orow = o0 + mi * 16 + lg * 4;
            int tcol = t0 + wid * 64 + ni * 16 + lr;
#pragma unroll
            for (int r = 0; r < 4; ++r) {
                out[((size_t)b * O_ + orow + r) * T_ + tcol] =
                    acc[mi][ni][r] + bias[orow + r];
            }
        }
    }
}

extern "C" void kernel_launch(void* const* d_in, const int* in_sizes, int n_in,
                              void* d_out, int out_size, void* d_ws, size_t ws_size,
                              hipStream_t stream) {
    const float* x    = (const float*)d_in[0];
    const float* w    = (const float*)d_in[1];
    const float* bias = (const float*)d_in[2];
    float* out        = (float*)d_out;

    unsigned short* wb  = (unsigned short*)d_ws;            // 2.62 MB
    unsigned short* xtp = wb + (size_t)KT * O_ * C_;        // 16*4128*512 bf16 = 67.7 MB

    prep_kernel<<<6144, 256, 0, stream>>>(w, wb, xtp);
    xtrans_kernel<<<dim3(T_ / 64, C_ / 64, B_), 256, 0, stream>>>(x, xtp);
    conv_gemm_kernel<<<512, 512, 0, stream>>>(wb, xtp, bias, out);
}